// Round 6
// baseline (37846.808 us; speedup 1.0000x reference)
//
#include <hip/hip_runtime.h>

#define SEQ    2048
#define BATCH  64
#define DIN    512
#define HID    512
#define GATES  2048      // 4*HID
#define NB     64        // block k owns 8 hidden cols -> 32 gate cols
#define NT     256       // 4 waves
#define TC     8         // x-projection chunk length (divides SEQ)
#define ZST    33        // padded f32 row stride for zxb

typedef short bf16v8 __attribute__((ext_vector_type(8)));
typedef float f32x4  __attribute__((ext_vector_type(4)));

static __device__ __forceinline__ unsigned short f2bfbits(float f) {
    union { __bf16 h; unsigned short s; } u;
    u.h = (__bf16)f;           // RNE
    return u.s;
}

static __device__ __forceinline__ bf16v8 cvt8(const float* __restrict__ p) {
    float4 a = *(const float4*)(p);
    float4 b = *(const float4*)(p + 4);
    union { __bf16 h[8]; bf16v8 v; } u;
    u.h[0] = (__bf16)a.x; u.h[1] = (__bf16)a.y;
    u.h[2] = (__bf16)a.z; u.h[3] = (__bf16)a.w;
    u.h[4] = (__bf16)b.x; u.h[5] = (__bf16)b.y;
    u.h[6] = (__bf16)b.z; u.h[7] = (__bf16)b.w;
    return u.v;
}

static __device__ __forceinline__ float sigm(float v) {
    return 1.0f / (1.0f + __expf(-v));
}
static __device__ __forceinline__ float ftanh(float v) {
    return 1.0f - 2.0f / (__expf(2.0f * v) + 1.0f);   // exact limits via __expf
}

// ============================ v6: tagged-h elastic pipeline =================
// h word = (bf16 << 16) | (version & 0xffff). Version v = t+1 is the INPUT
// to step t (h0 is v=1). Buffer v&1 holds version v. Writer of v needs all
// slots >= v-1 (slot[b] = last version block b fully READ) -- one step of
// elastic slack. No drains, no barrier flags on the data path.
__global__ void __launch_bounds__(NT, 1) lstm_v6(
    const float* __restrict__ x,  const float* __restrict__ c0,
    const float* __restrict__ h0, const float* __restrict__ Wi,
    const float* __restrict__ Wh, const float* __restrict__ bias,
    float* __restrict__ out, unsigned int* slots, unsigned int* htag)
{
    __shared__ unsigned short wi_lds[32 * 512];
    __shared__ unsigned short wh_lds[32 * 512];
    __shared__ float zxb[TC * 64 * ZST];
    __shared__ unsigned int hx[64 * 8];     // tagged h slice staging (2 KiB)

    const int tid   = threadIdx.x;
    const int blk   = blockIdx.x;
    const int lane  = tid & 63;
    const int wv    = tid >> 6;
    const int col   = lane & 15;
    const int rgrp  = lane >> 4;
    const int c7    = col & 7;
    const int hbase = blk * 8;

    for (int idx = tid; idx < 32 * 512; idx += NT) {
        const int c = idx & 31;
        const int k = idx >> 5;
        const int gc = (c >> 3) * HID + hbase + (c & 7);
        const int sidx = c * 512 + ((((k >> 3) ^ (c & 7)) << 3) | (k & 7));
        wi_lds[sidx] = f2bfbits(Wi[(size_t)k * GATES + gc]);
        wh_lds[sidx] = f2bfbits(Wh[(size_t)k * GATES + gc]);
    }

    // tagged h buffers: [2][64 kblk][64 row][8 col] u32
    unsigned int* hb0 = htag;
    unsigned int* hb1 = htag + 32768;
    // init h0 as version 1 into odd buffer; no barrier -- tags rendezvous
    for (int idx = blk * NT + tid; idx < 32768; idx += NB * NT) {
        const int kb = idx >> 9, row = (idx >> 3) & 63, j = idx & 7;
        const unsigned int w =
            ((unsigned int)f2bfbits(h0[row * HID + kb * 8 + j]) << 16) | 1u;
        __hip_atomic_store(&hb1[idx], w,
                           __ATOMIC_RELAXED, __HIP_MEMORY_SCOPE_AGENT);
    }

    const int brow_a = wv * 16 + col;
    const int hcol   = hbase + col;
    const float bv0 = bias[(col >> 3) * HID + hbase + c7];
    const float bv1 = bias[((col + 16) >> 3) * HID + hbase + c7];

    float cv[4];
    #pragma unroll
    for (int r = 0; r < 4; ++r) {
        const int brow = wv * 16 + rgrp * 4 + r;
        cv[r] = (col < 8) ? c0[brow * HID + hcol] : 0.0f;
    }

    const size_t YS = 2 * (size_t)BATCH * HID;

    for (int t0 = 0; t0 < SEQ; t0 += TC) {
        // ---- phase A: zxb = x_chunk @ Wi + bias (block-local, LDS) ----
        for (int m = wv; m < (TC * 64) >> 4; m += 4) {
            const float* xtile = x + ((size_t)t0 * 64 + m * 16 + col) * DIN;
            f32x4 a0 = {0.f, 0.f, 0.f, 0.f};
            f32x4 a1 = {0.f, 0.f, 0.f, 0.f};
            #pragma unroll
            for (int ks = 0; ks < 16; ++ks) {
                const int kofs = ks * 32 + rgrp * 8;
                bf16v8 axv = cvt8(xtile + kofs);
                const int gsw = (((ks * 4 + rgrp) ^ c7) << 3);
                bf16v8 b0 = *(const bf16v8*)(wi_lds + col * 512 + gsw);
                bf16v8 b1 = *(const bf16v8*)(wi_lds + (col + 16) * 512 + gsw);
                a0 = __builtin_amdgcn_mfma_f32_16x16x32_bf16(axv, b0, a0, 0, 0, 0);
                a1 = __builtin_amdgcn_mfma_f32_16x16x32_bf16(axv, b1, a1, 0, 0, 0);
            }
            #pragma unroll
            for (int r = 0; r < 4; ++r) {
                const int row = m * 16 + rgrp * 4 + r;
                zxb[row * ZST + col]      = a0[r] + bv0;
                zxb[row * ZST + col + 16] = a1[r] + bv1;
            }
        }
        __syncthreads();

        // ---- phase B ----
        for (int tt = 0; tt < TC; ++tt) {
            const int t = t0 + tt;
            const unsigned int vin  = (unsigned int)t + 1u;   // version to read
            const unsigned int texp = vin & 0xffffu;
            const unsigned int wtag = (vin + 1u) & 0xffffu;   // version written
            const unsigned int* hr  = (vin & 1u) ? hb1 : hb0;
            unsigned int*       hwt = (vin & 1u) ? hb0 : hb1; // (t+2)&1 == t&1

            // prefetch write-gate slot values (checked after compute)
            unsigned int gv = 0;
            if (wv == 0)
                gv = __hip_atomic_load(&slots[lane << 4],
                                       __ATOMIC_RELAXED, __HIP_MEMORY_SCOPE_AGENT);

            // ---- h read: optimistic load + tag-validate + pack ----
            unsigned int pa[16][4];
            #pragma unroll
            for (int hf = 0; hf < 2; ++hf) {
                unsigned long long q[32];
                const int ksb = hf * 8;
                #pragma unroll
                for (int k2 = 0; k2 < 8; ++k2) {
                    const unsigned long long* p = (const unsigned long long*)hr
                        + ((size_t)(((ksb + k2) * 4 + rgrp) * 64 + brow_a) << 2);
                    #pragma unroll
                    for (int j = 0; j < 4; ++j)
                        q[k2 * 4 + j] = __hip_atomic_load(p + j,
                            __ATOMIC_RELAXED, __HIP_MEMORY_SCOPE_AGENT);
                }
                while (true) {
                    bool ok = true;
                    #pragma unroll
                    for (int i = 0; i < 32; ++i)
                        ok = ok && (((unsigned int)q[i] & 0xffffu) == texp)
                                && (((unsigned int)(q[i] >> 32) & 0xffffu) == texp);
                    if (ok) break;
                    __builtin_amdgcn_s_sleep(1);
                    #pragma unroll
                    for (int k2 = 0; k2 < 8; ++k2) {
                        const unsigned long long* p = (const unsigned long long*)hr
                            + ((size_t)(((ksb + k2) * 4 + rgrp) * 64 + brow_a) << 2);
                        #pragma unroll
                        for (int j = 0; j < 4; ++j)
                            q[k2 * 4 + j] = __hip_atomic_load(p + j,
                                __ATOMIC_RELAXED, __HIP_MEMORY_SCOPE_AGENT);
                    }
                }
                #pragma unroll
                for (int k2 = 0; k2 < 8; ++k2)
                    #pragma unroll
                    for (int j = 0; j < 4; ++j) {
                        const unsigned long long qq = q[k2 * 4 + j];
                        pa[ksb + k2][j] =
                            ((unsigned int)(qq >> 32) & 0xffff0000u) |
                            ((unsigned int)qq >> 16);
                    }
            }

            // publish read-progress (off data path; gates writers one step on)
            __syncthreads();
            if (tid == 0)
                __hip_atomic_store(&slots[blk << 4], vin,
                                   __ATOMIC_RELAXED, __HIP_MEMORY_SCOPE_AGENT);

            f32x4 acc0, acc1;
            #pragma unroll
            for (int r = 0; r < 4; ++r) {
                const int row = tt * 64 + wv * 16 + rgrp * 4 + r;
                acc0[r] = zxb[row * ZST + col];
                acc1[r] = zxb[row * ZST + col + 16];
            }

            #pragma unroll
            for (int ks = 0; ks < 16; ++ks) {
                union { unsigned int w[4]; bf16v8 v; } hu;
                hu.w[0] = pa[ks][0]; hu.w[1] = pa[ks][1];
                hu.w[2] = pa[ks][2]; hu.w[3] = pa[ks][3];
                const int gsw = (((ks * 4 + rgrp) ^ c7) << 3);
                bf16v8 b0 = *(const bf16v8*)(wh_lds + col * 512 + gsw);
                bf16v8 b1 = *(const bf16v8*)(wh_lds + (col + 16) * 512 + gsw);
                acc0 = __builtin_amdgcn_mfma_f32_16x16x32_bf16(hu.v, b0, acc0, 0, 0, 0);
                acc1 = __builtin_amdgcn_mfma_f32_16x16x32_bf16(hu.v, b1, acc1, 0, 0, 0);
            }

            float zf[4], zo[4];
            #pragma unroll
            for (int r = 0; r < 4; ++r) {
                zf[r] = __shfl_xor(acc0[r], 8);
                zo[r] = __shfl_xor(acc1[r], 8);
            }

            float hn[4], cnl[4];
            if (col < 8) {
                #pragma unroll
                for (int r = 0; r < 4; ++r) {
                    const float ig = sigm(acc0[r]);
                    const float fg = sigm(zf[r]);
                    const float gg = ftanh(acc1[r]);
                    const float og = sigm(zo[r]);
                    const float cn = fg * cv[r] + ig * gg;
                    cv[r] = cn;
                    cnl[r] = cn;
                    hn[r] = og * ftanh(cn);
                    const int brow = wv * 16 + rgrp * 4 + r;
                    hx[brow * 8 + c7] =
                        ((unsigned int)f2bfbits(hn[r]) << 16) | wtag;
                }
            }
            __syncthreads();   // hx complete

            // ---- export: gate (1-step-lagged) then fire tagged slice ----
            if (wv == 0) {
                while (!__all(gv >= vin)) {
                    __builtin_amdgcn_s_sleep(1);
                    gv = __hip_atomic_load(&slots[lane << 4],
                                           __ATOMIC_RELAXED,
                                           __HIP_MEMORY_SCOPE_AGENT);
                }
                const unsigned int* sp = hx + lane * 8;
                unsigned long long* dst = (unsigned long long*)hwt
                    + ((size_t)(blk * 64 + lane) << 2);
                #pragma unroll
                for (int j = 0; j < 4; ++j) {
                    const unsigned long long e =
                        (unsigned long long)sp[2 * j] |
                        ((unsigned long long)sp[2 * j + 1] << 32);
                    __hip_atomic_store(dst + j, e,
                                       __ATOMIC_RELAXED, __HIP_MEMORY_SCOPE_AGENT);
                }
            }

            // ---- deferred outputs ----
            if (col < 8) {
                #pragma unroll
                for (int r = 0; r < 4; ++r) {
                    const int brow = wv * 16 + rgrp * 4 + r;
                    out[YS + ((size_t)t * BATCH + brow) * HID + hcol] = hn[r];
                    if (t == SEQ - 1) {
                        out[(size_t)brow * HID + hcol] = cnl[r];              // cT
                        out[(size_t)BATCH * HID + brow * HID + hcol] = hn[r]; // hT
                    }
                }
            }
        }
    }
}

// ===================== v5 fallback (proven, ws <= 132 KiB) ==================
__global__ void __launch_bounds__(NT, 1) lstm_v5(
    const float* __restrict__ x,  const float* __restrict__ c0,
    const float* __restrict__ h0, const float* __restrict__ Wi,
    const float* __restrict__ Wh, const float* __restrict__ bias,
    float* __restrict__ out, unsigned int* slots, unsigned short* hws)
{
    __shared__ unsigned short wi_lds[32 * 512];
    __shared__ unsigned short wh_lds[32 * 512];
    __shared__ float zxb[TC * 64 * ZST];
    __shared__ unsigned short hxch[64 * 8];

    const int tid   = threadIdx.x;
    const int blk   = blockIdx.x;
    const int lane  = tid & 63;
    const int wv    = tid >> 6;
    const int col   = lane & 15;
    const int rgrp  = lane >> 4;
    const int c7    = col & 7;
    const int hbase = blk * 8;

    for (int idx = tid; idx < 32 * 512; idx += NT) {
        const int c = idx & 31;
        const int k = idx >> 5;
        const int gc = (c >> 3) * HID + hbase + (c & 7);
        const int sidx = c * 512 + ((((k >> 3) ^ (c & 7)) << 3) | (k & 7));
        wi_lds[sidx] = f2bfbits(Wi[(size_t)k * GATES + gc]);
        wh_lds[sidx] = f2bfbits(Wh[(size_t)k * GATES + gc]);
    }

    unsigned short* hb0 = hws;
    unsigned short* hb1 = hws + 64 * 64 * 8;
    for (int idx = blk * NT + tid; idx < 64 * 64 * 8; idx += NB * NT) {
        const int kb = idx >> 9, row = (idx >> 3) & 63, j = idx & 7;
        __hip_atomic_store(&hb0[idx], f2bfbits(h0[row * HID + kb * 8 + j]),
                           __ATOMIC_RELAXED, __HIP_MEMORY_SCOPE_AGENT);
    }

    __syncthreads();
    if (tid == 0)
        __hip_atomic_store(&slots[blk << 4], 1u,
                           __ATOMIC_RELAXED, __HIP_MEMORY_SCOPE_AGENT);
    if (wv == 1) {
        unsigned int v;
        do {
            v = __hip_atomic_load(&slots[lane << 4],
                                  __ATOMIC_RELAXED, __HIP_MEMORY_SCOPE_AGENT);
        } while (!__all(v >= 1u));
    }
    __syncthreads();

    const int brow_a = wv * 16 + col;
    const int hcol   = hbase + col;
    const float bv0 = bias[(col >> 3) * HID + hbase + c7];
    const float bv1 = bias[((col + 16) >> 3) * HID + hbase + c7];

    float cv[4];
    #pragma unroll
    for (int r = 0; r < 4; ++r) {
        const int brow = wv * 16 + rgrp * 4 + r;
        cv[r] = (col < 8) ? c0[brow * HID + hcol] : 0.0f;
    }

    const size_t YS = 2 * (size_t)BATCH * HID;

    for (int t0 = 0; t0 < SEQ; t0 += TC) {
        for (int m = wv; m < (TC * 64) >> 4; m += 4) {
            const float* xtile = x + ((size_t)t0 * 64 + m * 16 + col) * DIN;
            f32x4 a0 = {0.f, 0.f, 0.f, 0.f};
            f32x4 a1 = {0.f, 0.f, 0.f, 0.f};
            #pragma unroll
            for (int ks = 0; ks < 16; ++ks) {
                const int kofs = ks * 32 + rgrp * 8;
                bf16v8 axv = cvt8(xtile + kofs);
                const int gsw = (((ks * 4 + rgrp) ^ c7) << 3);
                bf16v8 b0 = *(const bf16v8*)(wi_lds + col * 512 + gsw);
                bf16v8 b1 = *(const bf16v8*)(wi_lds + (col + 16) * 512 + gsw);
                a0 = __builtin_amdgcn_mfma_f32_16x16x32_bf16(axv, b0, a0, 0, 0, 0);
                a1 = __builtin_amdgcn_mfma_f32_16x16x32_bf16(axv, b1, a1, 0, 0, 0);
            }
            #pragma unroll
            for (int r = 0; r < 4; ++r) {
                const int row = m * 16 + rgrp * 4 + r;
                zxb[row * ZST + col]      = a0[r] + bv0;
                zxb[row * ZST + col + 16] = a1[r] + bv1;
            }
        }
        __syncthreads();

        for (int tt = 0; tt < TC; ++tt) {
            const int t = t0 + tt;
            const unsigned int kk = (unsigned int)t + 2u;
            const unsigned short* hr = (t & 1) ? hb1 : hb0;
            unsigned short*       hw = (t & 1) ? hb0 : hb1;

            unsigned long long hq0[16], hq1[16];
            {
                const unsigned long long* hsrc = (const unsigned long long*)hr;
                #pragma unroll
                for (int ks = 0; ks < 16; ++ks) {
                    const int kblk = ks * 4 + rgrp;
                    const unsigned long long* p =
                        hsrc + ((size_t)(kblk * 64 + brow_a) << 1);
                    hq0[ks] = __hip_atomic_load(p, __ATOMIC_RELAXED,
                                                __HIP_MEMORY_SCOPE_AGENT);
                    hq1[ks] = __hip_atomic_load(p + 1, __ATOMIC_RELAXED,
                                                __HIP_MEMORY_SCOPE_AGENT);
                }
            }

            f32x4 acc0, acc1;
            #pragma unroll
            for (int r = 0; r < 4; ++r) {
                const int row = tt * 64 + wv * 16 + rgrp * 4 + r;
                acc0[r] = zxb[row * ZST + col];
                acc1[r] = zxb[row * ZST + col + 16];
            }

            #pragma unroll
            for (int ks = 0; ks < 16; ++ks) {
                union { unsigned long long q[2]; bf16v8 v; } hu;
                hu.q[0] = hq0[ks];
                hu.q[1] = hq1[ks];
                const int gsw = (((ks * 4 + rgrp) ^ c7) << 3);
                bf16v8 b0 = *(const bf16v8*)(wh_lds + col * 512 + gsw);
                bf16v8 b1 = *(const bf16v8*)(wh_lds + (col + 16) * 512 + gsw);
                acc0 = __builtin_amdgcn_mfma_f32_16x16x32_bf16(hu.v, b0, acc0, 0, 0, 0);
                acc1 = __builtin_amdgcn_mfma_f32_16x16x32_bf16(hu.v, b1, acc1, 0, 0, 0);
            }

            float zf[4], zo[4];
            #pragma unroll
            for (int r = 0; r < 4; ++r) {
                zf[r] = __shfl_xor(acc0[r], 8);
                zo[r] = __shfl_xor(acc1[r], 8);
            }

            float hn[4], cnl[4];
            if (col < 8) {
                #pragma unroll
                for (int r = 0; r < 4; ++r) {
                    const float ig = sigm(acc0[r]);
                    const float fg = sigm(zf[r]);
                    const float gg = ftanh(acc1[r]);
                    const float og = sigm(zo[r]);
                    const float cn = fg * cv[r] + ig * gg;
                    cv[r] = cn;
                    cnl[r] = cn;
                    hn[r] = og * ftanh(cn);
                    const int brow = wv * 16 + rgrp * 4 + r;
                    hxch[brow * 8 + c7] = f2bfbits(hn[r]);
                }
            }
            __syncthreads();

            if (wv == 0) {
                const unsigned long long* sp =
                    (const unsigned long long*)(hxch + lane * 8);
                unsigned long long e0 = sp[0], e1 = sp[1];
                unsigned long long* dst = (unsigned long long*)
                    (hw + (((size_t)blk * 64 + lane) << 3));
                __hip_atomic_store(dst, e0, __ATOMIC_RELAXED,
                                   __HIP_MEMORY_SCOPE_AGENT);
                __hip_atomic_store(dst + 1, e1, __ATOMIC_RELAXED,
                                   __HIP_MEMORY_SCOPE_AGENT);
                asm volatile("s_waitcnt vmcnt(0)" ::: "memory");
                if (lane == 0)
                    __hip_atomic_store(&slots[blk << 4], kk,
                                       __ATOMIC_RELAXED,
                                       __HIP_MEMORY_SCOPE_AGENT);
            }

            if (col < 8) {
                #pragma unroll
                for (int r = 0; r < 4; ++r) {
                    const int brow = wv * 16 + rgrp * 4 + r;
                    out[YS + ((size_t)t * BATCH + brow) * HID + hcol] = hn[r];
                    if (t == SEQ - 1) {
                        out[(size_t)brow * HID + hcol] = cnl[r];
                        out[(size_t)BATCH * HID + brow * HID + hcol] = hn[r];
                    }
                }
            }

            if (wv == 1) {
                unsigned int v;
                do {
                    v = __hip_atomic_load(&slots[lane << 4],
                                          __ATOMIC_RELAXED,
                                          __HIP_MEMORY_SCOPE_AGENT);
                } while (!__all(v >= kk));
            }
            __syncthreads();
        }
    }
}

extern "C" void kernel_launch(void* const* d_in, const int* in_sizes, int n_in,
                              void* d_out, int out_size, void* d_ws, size_t ws_size,
                              hipStream_t stream) {
    const float* x  = (const float*)d_in[0];
    const float* c0 = (const float*)d_in[1];
    const float* h0 = (const float*)d_in[2];
    const float* Wi = (const float*)d_in[3];
    const float* Wh = (const float*)d_in[4];
    const float* b  = (const float*)d_in[5];
    float* out = (float*)d_out;

    char* wsb = (char*)d_ws;
    unsigned int* slots = (unsigned int*)wsb;

    const size_t v6_need = 4096 + 2ull * 32768 * sizeof(unsigned int); // 266 KB
    if (ws_size >= v6_need) {
        unsigned int* htag = (unsigned int*)(wsb + 4096);
        hipMemsetAsync(wsb, 0, v6_need, stream);   // tags+slots known-zero
        lstm_v6<<<dim3(NB), dim3(NT), 0, stream>>>(
            x, c0, h0, Wi, Wh, b, out, slots, htag);
    } else {
        unsigned short* hws = (unsigned short*)(wsb + 4096);
        hipMemsetAsync(slots, 0, 4096, stream);
        lstm_v5<<<dim3(NB), dim3(NT), 0, stream>>>(
            x, c0, h0, Wi, Wh, b, out, slots, hws);
    }
}

// Round 7
// 34776.056 us; speedup vs baseline: 1.0883x; 1.0883x over previous
//
#include <hip/hip_runtime.h>

#define SEQ    2048
#define BATCH  64
#define DIN    512
#define HID    512
#define GATES  2048      // 4*HID
#define NB     64        // block k owns 8 hidden cols -> 32 gate cols
#define NT     256       // 4 waves; wave w owns batch rows [16w,16w+16)
#define TC     8         // x-projection chunk length (divides SEQ)
#define ZST    33        // padded f32 row stride for zxb

typedef short bf16v8 __attribute__((ext_vector_type(8)));
typedef float f32x4  __attribute__((ext_vector_type(4)));

static __device__ __forceinline__ unsigned short f2bfbits(float f) {
    union { __bf16 h; unsigned short s; } u;
    u.h = (__bf16)f;           // RNE
    return u.s;
}

static __device__ __forceinline__ bf16v8 cvt8(const float* __restrict__ p) {
    float4 a = *(const float4*)(p);
    float4 b = *(const float4*)(p + 4);
    union { __bf16 h[8]; bf16v8 v; } u;
    u.h[0] = (__bf16)a.x; u.h[1] = (__bf16)a.y;
    u.h[2] = (__bf16)a.z; u.h[3] = (__bf16)a.w;
    u.h[4] = (__bf16)b.x; u.h[5] = (__bf16)b.y;
    u.h[6] = (__bf16)b.z; u.h[7] = (__bf16)b.w;
    return u.v;
}

static __device__ __forceinline__ float sigm(float v) {
    return 1.0f / (1.0f + __expf(-v));
}
static __device__ __forceinline__ float ftanh(float v) {
    return 1.0f - 2.0f / (__expf(2.0f * v) + 1.0f);   // exact limits via __expf
}

// ================= v7: wave-decoupled tagged-h elastic pipeline =============
// h word = (bf16 << 16) | version16. Version v = t+1 is the INPUT to step t
// (h0 = version 1, lives in buffer v&1). Each WAVE (not block) is a pipeline
// agent: wave w of block b reads its 16 batch rows of version v (validating
// tags, retrying stale 32B groups), publishes slot[w][b]=v, computes, and --
// gated on all slot[w][*] >= v-1 (overwrite target holds v-1) -- stores its
// 16x8 slice of version v+1. No __syncthreads, no flags, no drains in the
// loop; 1-step elastic slack absorbs inter-block jitter.
__global__ void __launch_bounds__(NT, 1) lstm_v7(
    const float* __restrict__ x,  const float* __restrict__ c0,
    const float* __restrict__ h0, const float* __restrict__ Wi,
    const float* __restrict__ Wh, const float* __restrict__ bias,
    float* __restrict__ out, unsigned int* slots, unsigned int* htag)
{
    __shared__ unsigned short wi_lds[32 * 512];
    __shared__ unsigned short wh_lds[32 * 512];
    __shared__ float zxb[TC * 64 * ZST];   // per-wave-private slices

    const int tid   = threadIdx.x;
    const int blk   = blockIdx.x;
    const int lane  = tid & 63;
    const int wv    = tid >> 6;
    const int col   = lane & 15;
    const int rgrp  = lane >> 4;
    const int c7    = col & 7;
    const int hbase = blk * 8;

    for (int idx = tid; idx < 32 * 512; idx += NT) {
        const int c = idx & 31;
        const int k = idx >> 5;
        const int gc = (c >> 3) * HID + hbase + (c & 7);
        const int sidx = c * 512 + ((((k >> 3) ^ (c & 7)) << 3) | (k & 7));
        wi_lds[sidx] = f2bfbits(Wi[(size_t)k * GATES + gc]);
        wh_lds[sidx] = f2bfbits(Wh[(size_t)k * GATES + gc]);
    }

    // tagged h buffers: [2][64 kblk][64 row][8 col] u32 (128 KiB each).
    // Block b seeds its own kblk=b slice with h0 as version 1 (buffer 1);
    // no barrier needed -- tags rendezvous.
    unsigned int* hb1 = htag + 32768;
    for (int idx = tid; idx < 512; idx += NT) {
        const int row = idx >> 3, j = idx & 7;
        const unsigned int w =
            ((unsigned int)f2bfbits(h0[row * HID + hbase + j]) << 16) | 1u;
        __hip_atomic_store(&hb1[(blk * 64 + row) * 8 + j], w,
                           __ATOMIC_RELAXED, __HIP_MEMORY_SCOPE_AGENT);
    }
    __syncthreads();   // weights ready (intra-block only)

    const int brow_a = wv * 16 + col;
    const int hcol   = hbase + col;
    const float bv0 = bias[(col >> 3) * HID + hbase + c7];
    const float bv1 = bias[((col + 16) >> 3) * HID + hbase + c7];

    float cv[4];
    #pragma unroll
    for (int r = 0; r < 4; ++r) {
        const int brow = wv * 16 + rgrp * 4 + r;
        cv[r] = (col < 8) ? c0[brow * HID + hcol] : 0.0f;
    }

    const size_t YS = 2 * (size_t)BATCH * HID;
    unsigned int* myslot  = &slots[(wv * 64 + blk) << 2];
    unsigned int* lnslot  = &slots[(wv * 64 + lane) << 2];

    for (int t0 = 0; t0 < SEQ; t0 += TC) {
        // ---- phase A: zxb slice = x_chunk @ Wi + bias (wave-private) ----
        for (int m = wv; m < (TC * 64) >> 4; m += 4) {
            const float* xtile = x + ((size_t)t0 * 64 + m * 16 + col) * DIN;
            f32x4 a0 = {0.f, 0.f, 0.f, 0.f};
            f32x4 a1 = {0.f, 0.f, 0.f, 0.f};
            #pragma unroll
            for (int ks = 0; ks < 16; ++ks) {
                const int kofs = ks * 32 + rgrp * 8;
                bf16v8 axv = cvt8(xtile + kofs);
                const int gsw = (((ks * 4 + rgrp) ^ c7) << 3);
                bf16v8 b0 = *(const bf16v8*)(wi_lds + col * 512 + gsw);
                bf16v8 b1 = *(const bf16v8*)(wi_lds + (col + 16) * 512 + gsw);
                a0 = __builtin_amdgcn_mfma_f32_16x16x32_bf16(axv, b0, a0, 0, 0, 0);
                a1 = __builtin_amdgcn_mfma_f32_16x16x32_bf16(axv, b1, a1, 0, 0, 0);
            }
            #pragma unroll
            for (int r = 0; r < 4; ++r) {
                const int row = m * 16 + rgrp * 4 + r;
                zxb[row * ZST + col]      = a0[r] + bv0;
                zxb[row * ZST + col + 16] = a1[r] + bv1;
            }
        }
        // no barrier: wave reads back only its own zxb rows

        // ---- phase B: free-running recurrence ----
        for (int tt = 0; tt < TC; ++tt) {
            const int t = t0 + tt;
            const unsigned int vin  = (unsigned int)t + 1u;
            const unsigned int texp = vin & 0xffffu;
            const unsigned int wtag = (vin + 1u) & 0xffffu;
            const unsigned int* hr  = htag + ((vin & 1u) << 15);
            unsigned int*       hwt = htag + (((vin + 1u) & 1u) << 15);

            // write-gate prefetch (checked much later; 1-step slack)
            unsigned int gv = __hip_atomic_load(lnslot, __ATOMIC_RELAXED,
                                                __HIP_MEMORY_SCOPE_AGENT);

            // ---- h read: optimistic bulk load + per-32B-group validate ----
            unsigned int pa[16][4];
            #pragma unroll
            for (int hf = 0; hf < 2; ++hf) {
                const int ksb = hf * 8;
                unsigned long long q[32];
                #pragma unroll
                for (int k2 = 0; k2 < 8; ++k2) {
                    const unsigned long long* p = (const unsigned long long*)hr
                        + ((size_t)(((ksb + k2) * 4 + rgrp) * 64 + brow_a) << 2);
                    #pragma unroll
                    for (int j = 0; j < 4; ++j)
                        q[k2 * 4 + j] = __hip_atomic_load(p + j,
                            __ATOMIC_RELAXED, __HIP_MEMORY_SCOPE_AGENT);
                }
                #pragma unroll
                for (int k2 = 0; k2 < 8; ++k2) {
                    const unsigned long long* p = (const unsigned long long*)hr
                        + ((size_t)(((ksb + k2) * 4 + rgrp) * 64 + brow_a) << 2);
                    while (true) {
                        bool ok = true;
                        #pragma unroll
                        for (int j = 0; j < 4; ++j) {
                            const unsigned int lo = (unsigned int)q[k2 * 4 + j];
                            const unsigned int hi =
                                (unsigned int)(q[k2 * 4 + j] >> 32);
                            ok = ok && ((lo & 0xffffu) == texp)
                                    && ((hi & 0xffffu) == texp);
                        }
                        if (ok) break;
                        __builtin_amdgcn_s_sleep(1);
                        #pragma unroll
                        for (int j = 0; j < 4; ++j)
                            q[k2 * 4 + j] = __hip_atomic_load(p + j,
                                __ATOMIC_RELAXED, __HIP_MEMORY_SCOPE_AGENT);
                    }
                    #pragma unroll
                    for (int j = 0; j < 4; ++j) {
                        const unsigned long long qq = q[k2 * 4 + j];
                        pa[ksb + k2][j] =
                            ((unsigned int)(qq >> 32) & 0xffff0000u) |
                            ((unsigned int)qq >> 16);
                    }
                }
            }

            // publish read-progress for this wave (enables overwrites of vin)
            if (lane == 0)
                __hip_atomic_store(myslot, vin,
                                   __ATOMIC_RELAXED, __HIP_MEMORY_SCOPE_AGENT);

            f32x4 acc0, acc1;
            #pragma unroll
            for (int r = 0; r < 4; ++r) {
                const int row = tt * 64 + wv * 16 + rgrp * 4 + r;
                acc0[r] = zxb[row * ZST + col];
                acc1[r] = zxb[row * ZST + col + 16];
            }

            #pragma unroll
            for (int ks = 0; ks < 16; ++ks) {
                union { unsigned int w[4]; bf16v8 v; } hu;
                hu.w[0] = pa[ks][0]; hu.w[1] = pa[ks][1];
                hu.w[2] = pa[ks][2]; hu.w[3] = pa[ks][3];
                const int gsw = (((ks * 4 + rgrp) ^ c7) << 3);
                bf16v8 b0 = *(const bf16v8*)(wh_lds + col * 512 + gsw);
                bf16v8 b1 = *(const bf16v8*)(wh_lds + (col + 16) * 512 + gsw);
                acc0 = __builtin_amdgcn_mfma_f32_16x16x32_bf16(hu.v, b0, acc0, 0, 0, 0);
                acc1 = __builtin_amdgcn_mfma_f32_16x16x32_bf16(hu.v, b1, acc1, 0, 0, 0);
            }

            float zf[4], zo[4];
            #pragma unroll
            for (int r = 0; r < 4; ++r) {
                zf[r] = __shfl_xor(acc0[r], 8);   // partner col+8: f gate
                zo[r] = __shfl_xor(acc1[r], 8);   // partner col+24: o gate
            }

            float hn[4], cnl[4];
            if (col < 8) {
                #pragma unroll
                for (int r = 0; r < 4; ++r) {
                    const float ig = sigm(acc0[r]);
                    const float fg = sigm(zf[r]);
                    const float gg = ftanh(acc1[r]);
                    const float og = sigm(zo[r]);
                    const float cn = fg * cv[r] + ig * gg;
                    cv[r] = cn;
                    cnl[r] = cn;
                    hn[r] = og * ftanh(cn);
                }
            }

            // ---- write gate: overwrite target holds version vin-1 ----
            while (!__all(gv >= vin - 1u)) {
                __builtin_amdgcn_s_sleep(1);
                gv = __hip_atomic_load(lnslot, __ATOMIC_RELAXED,
                                       __HIP_MEMORY_SCOPE_AGENT);
            }

            // ---- export: tagged slice, straight from registers ----
            if (col < 8) {
                #pragma unroll
                for (int r = 0; r < 4; ++r) {
                    const int brow = wv * 16 + rgrp * 4 + r;
                    const unsigned int w =
                        ((unsigned int)f2bfbits(hn[r]) << 16) | wtag;
                    __hip_atomic_store(&hwt[(blk * 64 + brow) * 8 + c7], w,
                                       __ATOMIC_RELAXED, __HIP_MEMORY_SCOPE_AGENT);
                }
                // deferred outputs (latency overlapped with next step)
                #pragma unroll
                for (int r = 0; r < 4; ++r) {
                    const int brow = wv * 16 + rgrp * 4 + r;
                    out[YS + ((size_t)t * BATCH + brow) * HID + hcol] = hn[r];
                    if (t == SEQ - 1) {
                        out[(size_t)brow * HID + hcol] = cnl[r];              // cT
                        out[(size_t)BATCH * HID + brow * HID + hcol] = hn[r]; // hT
                    }
                }
            }
        }
    }
}

extern "C" void kernel_launch(void* const* d_in, const int* in_sizes, int n_in,
                              void* d_out, int out_size, void* d_ws, size_t ws_size,
                              hipStream_t stream) {
    const float* x  = (const float*)d_in[0];
    const float* c0 = (const float*)d_in[1];
    const float* h0 = (const float*)d_in[2];
    const float* Wi = (const float*)d_in[3];
    const float* Wh = (const float*)d_in[4];
    const float* b  = (const float*)d_in[5];
    float* out = (float*)d_out;

    // ws: [0,4K) 256 wave-slots (16B spaced) | [4K, 4K+256K) 2 tagged h bufs
    char* wsb = (char*)d_ws;
    unsigned int* slots = (unsigned int*)wsb;
    unsigned int* htag  = (unsigned int*)(wsb + 4096);

    const size_t need = 4096 + 2ull * 32768 * sizeof(unsigned int); // 266,240 B
    // tags/slots MUST be zero each call (stale tags from a previous replay
    // would false-positive: versions repeat across calls)
    hipMemsetAsync(wsb, 0, need, stream);

    lstm_v7<<<dim3(NB), dim3(NT), 0, stream>>>(
        x, c0, h0, Wi, Wh, b, out, slots, htag);
}

// Round 10
// 28707.169 us; speedup vs baseline: 1.3184x; 1.2114x over previous
//
#include <hip/hip_runtime.h>

#define SEQ    2048
#define BATCH  64
#define DIN    512
#define HID    512
#define GATES  2048
#define NBLK   256      // 8 XCD groups x 32 slots (1 block/CU, coop-resident)
#define NT     256      // 4 waves
#define TC     8        // x-projection chunk length
#define ZST    65       // zxb row stride (f32)

typedef short bf16v8 __attribute__((ext_vector_type(8)));
typedef float f32x4  __attribute__((ext_vector_type(4)));

static __device__ __forceinline__ unsigned short f2bfbits(float f) {
    union { __bf16 h; unsigned short s; } u;
    u.h = (__bf16)f;           // RNE
    return u.s;
}

static __device__ __forceinline__ bf16v8 cvt8(const float* __restrict__ p) {
    float4 a = *(const float4*)(p);
    float4 b = *(const float4*)(p + 4);
    union { __bf16 h[8]; bf16v8 v; } u;
    u.h[0] = (__bf16)a.x; u.h[1] = (__bf16)a.y;
    u.h[2] = (__bf16)a.z; u.h[3] = (__bf16)a.w;
    u.h[4] = (__bf16)b.x; u.h[5] = (__bf16)b.y;
    u.h[6] = (__bf16)b.z; u.h[7] = (__bf16)b.w;
    return u.v;
}

static __device__ __forceinline__ float sigm(float v) {
    return 1.0f / (1.0f + __expf(-v));
}
static __device__ __forceinline__ float ftanh(float v) {
    return 1.0f - 2.0f / (__expf(2.0f * v) + 1.0f);
}

// ============ v9: XCD-local groups, L2-executing atomic primitives ==========
// XCD x owns batch rows [8x,8x+8); slot s (0..31) owns hidden cols
// [16s,16s+16). Cross-block signaling within an XCD uses workgroup-scope
// atomic RMWs (execute at the shared L2, structurally bypass L1 -- no sc0
// hints). h writes are plain write-through stores; h reads are +0 RMWs.
// All spins are watchdogged (sticky abort -> fast wrong-answer, not hang).
__global__ void __launch_bounds__(NT, 1) lstm_v9(
    const float* __restrict__ x,  const float* __restrict__ c0,
    const float* __restrict__ h0, const float* __restrict__ Wi,
    const float* __restrict__ Wh, const float* __restrict__ bias,
    float* __restrict__ out, unsigned int* flags, unsigned int* mall,
    unsigned int* claim, unsigned short* hglob)
{
    __shared__ unsigned short wi_lds[64 * 512];   // 64 KB
    __shared__ unsigned short wh_lds[64 * 512];   // 64 KB
    __shared__ float zxb[64 * ZST];               // 16.25 KB
    __shared__ unsigned short h_lds[8 * 512];     // 8 KB, swizzled
    __shared__ float ys_lds[TC * 8 * 16];         // 4 KB
    __shared__ int xs_lds[2];
    __shared__ int abortf;

    const int tid  = threadIdx.x;
    const int lane = tid & 63;
    const int wv   = tid >> 6;
    const int col  = lane & 15;
    const int rgrp = lane >> 4;
    const int c7   = col & 7;
    const int c3   = col & 3;

    // laundered zeros: keep fetch_add(+0) a real RMW (L2-executing)
    unsigned int zu = 0;        asm volatile("" : "+v"(zu));
    unsigned long long zl = 0;  asm volatile("" : "+v"(zl));

    // ---- claim role from actual placement ----
    unsigned int xcd;
    asm volatile("s_getreg_b32 %0, hwreg(HW_REG_XCC_ID)" : "=s"(xcd));
    if (tid == 0) {
        abortf = 0;
        unsigned int slot = __hip_atomic_fetch_add(&claim[(xcd & 7) * 16], 1u,
                               __ATOMIC_RELAXED, __HIP_MEMORY_SCOPE_AGENT);
        xs_lds[0] = (int)(xcd & 7);
        xs_lds[1] = (int)(slot & 31);
    }
    __syncthreads();
    const int x_ = xs_lds[0];
    const int s_ = xs_lds[1];

    // ---- weights: 64 gate cols; lc = w*16 + type*4 + jj -> hidden 16s+4w+jj
    for (int idx = tid; idx < 64 * 512; idx += NT) {
        const int lc = idx & 63, k = idx >> 6;
        const int c = lc & 15, w = lc >> 4;
        const int gc = (c >> 2) * HID + s_ * 16 + w * 4 + (c & 3);
        const int sidx = lc * 512 + ((((k >> 3) ^ (c & 7)) << 3) | (k & 7));
        wi_lds[sidx] = f2bfbits(Wi[(size_t)k * GATES + gc]);
        wh_lds[sidx] = f2bfbits(Wh[(size_t)k * GATES + gc]);
    }

    // clean own flag: exchange forces 0 in every cache-state interleaving
    if (tid == 0)
        (void)__hip_atomic_exchange(&flags[(x_ * 32 + s_) * 16], 0u,
                                    __ATOMIC_RELAXED,
                                    __HIP_MEMORY_SCOPE_WORKGROUP);

    // seed h_0 slice into buf 0 (plain write-through stores)
    if (tid < 128) {
        const int row = tid >> 4, j = tid & 15;
        hglob[(x_ * 8 + row) * 512 + s_ * 16 + j] =
            f2bfbits(h0[(8 * x_ + row) * HID + s_ * 16 + j]);
    }
    asm volatile("s_waitcnt vmcnt(0)" ::: "memory");
    __syncthreads();

    // one-time MALL rendezvous (proven agent-atomic pattern), watchdogged
    if (tid == 0)
        __hip_atomic_store(&mall[(x_ * 32 + s_) * 16], 1u,
                           __ATOMIC_RELAXED, __HIP_MEMORY_SCOPE_AGENT);
    if (wv == 0) {
        int guard = 0;
        unsigned int v;
        do {
            v = __hip_atomic_load(&mall[(x_ * 32 + (lane & 31)) * 16],
                                  __ATOMIC_RELAXED, __HIP_MEMORY_SCOPE_AGENT);
            if (__all(v >= 1u)) break;
            __builtin_amdgcn_s_sleep(8);
        } while (++guard < (1 << 20));
        if (guard >= (1 << 20)) abortf = 1;
    }
    __syncthreads();
    if (tid == 0)
        __hip_atomic_store(&flags[(x_ * 32 + s_) * 16], 1u,
                           __ATOMIC_RELAXED, __HIP_MEMORY_SCOPE_WORKGROUP);

    // ---- hoist Wh fragments (loop-invariant; 1 wave/SIMD so VGPRs free)
    bf16v8 whf[16];
    #pragma unroll
    for (int ks = 0; ks < 16; ++ks)
        whf[ks] = *(const bf16v8*)(wh_lds + (wv * 16 + col) * 512 +
                                   (((ks * 4 + rgrp) ^ c7) << 3));

    float bvA[4];
    #pragma unroll
    for (int g = 0; g < 4; ++g)
        bvA[g] = bias[(col >> 2) * HID + s_ * 16 + g * 4 + c3];

    const int hcol = s_ * 16 + 4 * wv + col;
    const bool act = (col < 4) && (rgrp < 2);
    float cv[4];
    #pragma unroll
    for (int r = 0; r < 4; ++r)
        cv[r] = act ? c0[(8 * x_ + rgrp * 4 + r) * HID + hcol] : 0.0f;

    for (int t0 = 0; t0 < SEQ; t0 += TC) {
        // ---- flush previous chunk's ys (off the critical path) ----
        if (t0 > 0) {
            const int ft = tid >> 5, fr = (tid >> 2) & 7, fc = (tid & 3) * 4;
            const float4 v = *(const float4*)(ys_lds + (ft * 8 + fr) * 16 + fc);
            *(float4*)(out + 2 * (size_t)BATCH * HID +
                       ((size_t)(t0 - TC + ft) * BATCH + 8 * x_ + fr) * HID +
                       s_ * 16 + fc) = v;
        }

        // ---- phase A: wave wv -> zxb rows [16wv,16wv+16) x 64 cols ----
        {
            f32x4 za0 = {0,0,0,0}, za1 = {0,0,0,0}, za2 = {0,0,0,0}, za3 = {0,0,0,0};
            const int rr = wv * 16 + col;
            const float* xrow = x + ((size_t)(t0 + (rr >> 3)) * BATCH +
                                     8 * x_ + (rr & 7)) * DIN;
            #pragma unroll
            for (int ks = 0; ks < 16; ++ks) {
                const bf16v8 axv = cvt8(xrow + ks * 32 + rgrp * 8);
                const int gsw = ((ks * 4 + rgrp) ^ c7) << 3;
                const bf16v8 b0 = *(const bf16v8*)(wi_lds + (col) * 512 + gsw);
                const bf16v8 b1 = *(const bf16v8*)(wi_lds + (16 + col) * 512 + gsw);
                const bf16v8 b2 = *(const bf16v8*)(wi_lds + (32 + col) * 512 + gsw);
                const bf16v8 b3 = *(const bf16v8*)(wi_lds + (48 + col) * 512 + gsw);
                za0 = __builtin_amdgcn_mfma_f32_16x16x32_bf16(axv, b0, za0, 0, 0, 0);
                za1 = __builtin_amdgcn_mfma_f32_16x16x32_bf16(axv, b1, za1, 0, 0, 0);
                za2 = __builtin_amdgcn_mfma_f32_16x16x32_bf16(axv, b2, za2, 0, 0, 0);
                za3 = __builtin_amdgcn_mfma_f32_16x16x32_bf16(axv, b3, za3, 0, 0, 0);
            }
            #pragma unroll
            for (int r = 0; r < 4; ++r) {
                const int zr = (wv * 16 + rgrp * 4 + r) * ZST;
                zxb[zr + col]      = za0[r] + bvA[0];
                zxb[zr + 16 + col] = za1[r] + bvA[1];
                zxb[zr + 32 + col] = za2[r] + bvA[2];
                zxb[zr + 48 + col] = za3[r] + bvA[3];
            }
        }
        __syncthreads();

        // ---- phase B: recurrence ----
        for (int tt = 0; tt < TC; ++tt) {
            const int t = t0 + tt;

            // poll group flags >= t+1 via L2-executing RMW (watchdogged)
            if (wv == 0 && !abortf) {
                const unsigned int tgt = (unsigned int)t + 1u;
                unsigned int* fp = &flags[(x_ * 32 + (lane & 31)) * 16];
                int guard = 0;
                unsigned int v = __hip_atomic_fetch_add(fp, zu,
                        __ATOMIC_RELAXED, __HIP_MEMORY_SCOPE_WORKGROUP);
                while (!__all(v >= tgt)) {
                    if (++guard > (1 << 22)) { abortf = 1; break; }
                    __builtin_amdgcn_s_sleep(1);
                    v = __hip_atomic_fetch_add(fp, zu,
                            __ATOMIC_RELAXED, __HIP_MEMORY_SCOPE_WORKGROUP);
                }
            }
            __syncthreads();

            // stage h_t (buf t&1) -> h_lds via +0 u64 RMWs (L1-proof)
            {
                const int row = tid >> 5, ks2 = (tid >> 1) & 15, rg0 = (tid & 1) * 2;
                unsigned long long* src = (unsigned long long*)
                    (hglob + (((t & 1) * 8 + x_) * 8 + row) * 512)
                    + (ks2 * 8 + rg0 * 2);
                const unsigned long long q0 = __hip_atomic_fetch_add(src + 0, zl,
                        __ATOMIC_RELAXED, __HIP_MEMORY_SCOPE_WORKGROUP);
                const unsigned long long q1 = __hip_atomic_fetch_add(src + 1, zl,
                        __ATOMIC_RELAXED, __HIP_MEMORY_SCOPE_WORKGROUP);
                const unsigned long long q2 = __hip_atomic_fetch_add(src + 2, zl,
                        __ATOMIC_RELAXED, __HIP_MEMORY_SCOPE_WORKGROUP);
                const unsigned long long q3 = __hip_atomic_fetch_add(src + 3, zl,
                        __ATOMIC_RELAXED, __HIP_MEMORY_SCOPE_WORKGROUP);
                const int base = row * 512 + ks2 * 32;
                unsigned long long* d0 = (unsigned long long*)
                    (h_lds + base + ((rg0 ^ (row & 3)) << 3));
                d0[0] = q0; d0[1] = q1;
                unsigned long long* d1 = (unsigned long long*)
                    (h_lds + base + (((rg0 + 1) ^ (row & 3)) << 3));
                d1[0] = q2; d1[1] = q3;
            }
            __syncthreads();

            // z = zxb(+bias) + h @ Wh
            f32x4 accA, accB = {0, 0, 0, 0};
            {
                const int zr = (tt * 8 + (rgrp & 1) * 4) * ZST + wv * 16 + col;
                accA[0] = zxb[zr];           accA[1] = zxb[zr + ZST];
                accA[2] = zxb[zr + 2 * ZST]; accA[3] = zxb[zr + 3 * ZST];
            }
            const int abase = (col & 7) * 512 + ((rgrp ^ c3) << 3);
            #pragma unroll
            for (int ks = 0; ks < 16; ks += 2) {
                const bf16v8 a0 = *(const bf16v8*)(h_lds + abase + ks * 32);
                const bf16v8 a1 = *(const bf16v8*)(h_lds + abase + ks * 32 + 32);
                accA = __builtin_amdgcn_mfma_f32_16x16x32_bf16(a0, whf[ks],     accA, 0, 0, 0);
                accB = __builtin_amdgcn_mfma_f32_16x16x32_bf16(a1, whf[ks + 1], accB, 0, 0, 0);
            }

            float z[4], zf[4], zg[4], zo[4];
            #pragma unroll
            for (int r = 0; r < 4; ++r) z[r] = accA[r] + accB[r];
            #pragma unroll
            for (int r = 0; r < 4; ++r) {
                zf[r] = __shfl_xor(z[r], 4);    // f gate
                zg[r] = __shfl_xor(z[r], 8);    // g gate
                zo[r] = __shfl_xor(z[r], 12);   // o gate
            }

            if (act) {
                #pragma unroll
                for (int r = 0; r < 4; ++r) {
                    const float ig = sigm(z[r]);
                    const float fg = sigm(zf[r]);
                    const float gg = ftanh(zg[r]);
                    const float og = sigm(zo[r]);
                    const float cn = fg * cv[r] + ig * gg;
                    cv[r] = cn;
                    const float hn = og * ftanh(cn);
                    const int row = rgrp * 4 + r;
                    hglob[((((t + 1) & 1) * 8 + x_) * 8 + row) * 512 + hcol] =
                        f2bfbits(hn);                          // plain, write-through
                    ys_lds[(tt * 8 + row) * 16 + 4 * wv + col] = hn;
                    if (t == SEQ - 1) {
                        out[(size_t)(8 * x_ + row) * HID + hcol] = cn;                    // cT
                        out[(size_t)BATCH * HID + (size_t)(8 * x_ + row) * HID + hcol] = hn; // hT
                    }
                }
            }
            // drain ALL waves' h stores to L2, then publish
            asm volatile("s_waitcnt vmcnt(0)" ::: "memory");
            __syncthreads();
            if (tid == 0)
                __hip_atomic_store(&flags[(x_ * 32 + s_) * 16],
                                   (unsigned int)t + 2u,
                                   __ATOMIC_RELAXED,
                                   __HIP_MEMORY_SCOPE_WORKGROUP);
        }
    }

    // ---- final ys flush ----
    __syncthreads();
    {
        const int ft = tid >> 5, fr = (tid >> 2) & 7, fc = (tid & 3) * 4;
        const float4 v = *(const float4*)(ys_lds + (ft * 8 + fr) * 16 + fc);
        *(float4*)(out + 2 * (size_t)BATCH * HID +
                   ((size_t)(SEQ - TC + ft) * BATCH + 8 * x_ + fr) * HID +
                   s_ * 16 + fc) = v;
    }
}

extern "C" void kernel_launch(void* const* d_in, const int* in_sizes, int n_in,
                              void* d_out, int out_size, void* d_ws, size_t ws_size,
                              hipStream_t stream) {
    const float* x  = (const float*)d_in[0];
    const float* c0 = (const float*)d_in[1];
    const float* h0 = (const float*)d_in[2];
    const float* Wi = (const float*)d_in[3];
    const float* Wh = (const float*)d_in[4];
    const float* b  = (const float*)d_in[5];
    float* out = (float*)d_out;

    // ws: [0,16K) flags | [16K,32K) MALL rendezvous | [32K,+512) claim
    //     [36864, +128K) h double buffer [2][8 xcd][8 row][512] bf16
    char* wsb = (char*)d_ws;
    unsigned int* flags   = (unsigned int*)wsb;
    unsigned int* mall    = (unsigned int*)(wsb + 16384);
    unsigned int* claim   = (unsigned int*)(wsb + 32768);
    unsigned short* hglob = (unsigned short*)(wsb + 36864);

    (void)hipMemsetAsync(wsb, 0, 33280, stream);   // flags + mall + claim

    void* args[] = { (void*)&x, (void*)&c0, (void*)&h0, (void*)&Wi,
                     (void*)&Wh, (void*)&b, (void*)&out, (void*)&flags,
                     (void*)&mall, (void*)&claim, (void*)&hglob };
    (void)hipLaunchCooperativeKernel((void*)lstm_v9, dim3(NBLK), dim3(NT),
                                     args, 0, stream);
}